// Round 7
// baseline (177.953 us; speedup 1.0000x reference)
//
#include <hip/hip_runtime.h>
#include <hip/hip_bf16.h>
#include <math.h>

#define N_NODES 50000
#define N_EDGES 600000
#define D_IN 256
#define D_GNN 128
#define CAP 32        // padded adjacency slots per node (ushort); 1 cache line
#define MAX_OVER 8192
#define EDGE_BLKS 64  // dedicated edge-build blocks (dispatched first)

typedef short s16x8 __attribute__((ext_vector_type(8)));
typedef float f32x4 __attribute__((ext_vector_type(4)));

__device__ __forceinline__ unsigned short f2bf(float f) {
  unsigned int u = __float_as_uint(f);
  u += 0x7FFFu + ((u >> 16) & 1u);  // RNE
  return (unsigned short)(u >> 16);
}

// ---------------------------------------------------------------------------
// Prologue: zero cursor[] + overflow count + pack Wc=[W_l|W_r] to B-fragment
// order (bf16): Wcp[((ks*256+col)*4+q)*8+j] = [Wl|Wr][ks*32+q*8+j][col]
// ---------------------------------------------------------------------------
__global__ __launch_bounds__(256) void pack0(
    const float* __restrict__ Wl, const float* __restrict__ Wr,
    ushort* __restrict__ Wcp, int* __restrict__ cursor,
    int* __restrict__ ovcnt) {
  int i = blockIdx.x * 256 + threadIdx.x;
  if (i < N_NODES) cursor[i] = 0;
  if (i == 0) ovcnt[0] = 0;
  if (i < 8192) {  // one 16B B-fragment per thread
    int q = i & 3, col = (i >> 2) & 255, ks = i >> 10;
    const float* W = (col < 128) ? Wl : Wr;
    int c = col & 127;
    int k0 = ks * 32 + q * 8;
    s16x8 v;
#pragma unroll
    for (int j = 0; j < 8; j++) v[j] = (short)f2bf(W[(k0 + j) * D_GNN + c]);
    *((s16x8*)(Wcp + (size_t)i * 8)) = v;
  }
}

// ---------------------------------------------------------------------------
// FUSED kernel (R7): BLOCK-SPECIALIZED edge build + MFMA GEMM.
//   R6 lesson: cursor line-padding regressed fused 56->63 (atomic cost is
//   round-trip latency at the coherence point, not same-line contention) ->
//   reverted to compact cursor. R2 lesson: edge work inside GEMM blocks puts
//   the atomic round-trip + scatter store on every block's vmcnt(0) barrier
//   (+12us over the 44us pure GEMM).
//   Fix: blocks 0..63 (dispatched FIRST, run concurrent with early GEMM
//   waves) own ALL 600K edges, ~18/thread, 4 atomics in flight via manual
//   x4 unroll (~10us, hidden under GEMM). Blocks 64+ run the R2-proven GEMM
//   with ZERO atomic/scatter code on their critical path.
//   GEMM: [y_l|y_r] = x @ [W_l|W_r]; block = 64 rows x 256 cols, 8 waves;
//   x staged f32->LDS via async global_load_lds w=16 (source-chunk swizzle,
//   read-side same involution); bf16 cvt at A-read; B prefetch 1 K-step.
//   Epilogue: acc -> LDS bf16 (padded stride 264) -> b128 stores.
// ---------------------------------------------------------------------------
__global__ __launch_bounds__(512, 4) void fused_gemm_fill(
    const float* __restrict__ x, const ushort* __restrict__ Wcp,
    const float* __restrict__ b_l, const int* __restrict__ ei,
    int* __restrict__ cursor, ushort* __restrict__ colp,
    int* __restrict__ ovcnt, int2* __restrict__ over,
    ushort* __restrict__ yb, ushort* __restrict__ yrb) {
  __shared__ float xs[64 * 256];  // 64 KiB staging; epilogue aliases as bf16
  const int t = threadIdx.x;

  // ========== edge-build blocks: all edges, nothing else ==========
  if (blockIdx.x < EDGE_BLKS) {
    const int stride = EDGE_BLKS * 512;
    int e = blockIdx.x * 512 + t;
    // x4 unrolled: 4 independent atomic+store chains in flight
    for (; e + 3 * stride < N_EDGES; e += 4 * stride) {
      int s0 = ei[e],              d0 = ei[N_EDGES + e];
      int s1 = ei[e + stride],     d1 = ei[N_EDGES + e + stride];
      int s2 = ei[e + 2 * stride], d2 = ei[N_EDGES + e + 2 * stride];
      int s3 = ei[e + 3 * stride], d3 = ei[N_EDGES + e + 3 * stride];
      int p0 = atomicAdd(&cursor[d0], 1);
      int p1 = atomicAdd(&cursor[d1], 1);
      int p2 = atomicAdd(&cursor[d2], 1);
      int p3 = atomicAdd(&cursor[d3], 1);
      if (p0 < CAP) colp[d0 * CAP + p0] = (ushort)s0;
      else { int o = atomicAdd(ovcnt, 1); if (o < MAX_OVER) over[o] = make_int2(d0, s0); }
      if (p1 < CAP) colp[d1 * CAP + p1] = (ushort)s1;
      else { int o = atomicAdd(ovcnt, 1); if (o < MAX_OVER) over[o] = make_int2(d1, s1); }
      if (p2 < CAP) colp[d2 * CAP + p2] = (ushort)s2;
      else { int o = atomicAdd(ovcnt, 1); if (o < MAX_OVER) over[o] = make_int2(d2, s2); }
      if (p3 < CAP) colp[d3 * CAP + p3] = (ushort)s3;
      else { int o = atomicAdd(ovcnt, 1); if (o < MAX_OVER) over[o] = make_int2(d3, s3); }
    }
    for (; e < N_EDGES; e += stride) {
      int src = ei[e];
      int dst = ei[N_EDGES + e];
      int pos = atomicAdd(&cursor[dst], 1);
      if (pos < CAP) colp[dst * CAP + pos] = (ushort)src;
      else { int o = atomicAdd(ovcnt, 1); if (o < MAX_OVER) over[o] = make_int2(dst, src); }
    }
    return;
  }

  // ========== GEMM blocks: pure R2 structure, no atomics ==========
  const int n0 = (blockIdx.x - EDGE_BLKS) * 64;
  const int l = t & 63;
  const int w = t >> 6;

  // --- 1. async stage x -> LDS (f32, source-chunk swizzled) ---
#pragma unroll
  for (int j = 0; j < 8; j++) {
    const int row = j * 8 + w;
    int gn = n0 + row;
    if (gn >= N_NODES) gn = N_NODES - 1;  // clamp; stores guarded
    const int sc = (l & ~7) | ((l & 7) ^ (row & 7));
    __builtin_amdgcn_global_load_lds(
        (const __attribute__((address_space(1))) unsigned int*)(
            x + (size_t)gn * 256 + sc * 4),
        (__attribute__((address_space(3))) unsigned int*)(xs + row * 256),
        16, 0, 0);
  }

  const int wrow = w & 1;
  const int wcol = w >> 1;
  const int lq = l >> 4, l16 = l & 15;

  f32x4 acc[2][4];
#pragma unroll
  for (int a = 0; a < 2; a++)
#pragma unroll
    for (int b = 0; b < 4; b++) acc[a][b] = (f32x4){0.f, 0.f, 0.f, 0.f};

  // A-read bases: row rl, chunk pair (ks*8 + o0), o0 = (lq*2)^(rl&7).
  const float* ap0[2];
  const float* ap1[2];
#pragma unroll
  for (int nt = 0; nt < 2; nt++) {
    int rl = wrow * 32 + nt * 16 + l16;
    int o0 = (lq * 2) ^ (rl & 7);
    ap0[nt] = xs + rl * 256 + o0 * 4;
    ap1[nt] = xs + rl * 256 + (o0 ^ 1) * 4;
  }
  const ushort* bptr[4];
#pragma unroll
  for (int ct = 0; ct < 4; ct++) {
    int col = wcol * 64 + ct * 16 + l16;
    bptr[ct] = Wcp + ((size_t)col * 4 + lq) * 8;
  }

  // First B fragments before the barrier: overlap L2 latency with drain.
  s16x8 B[4], Bn[4];
#pragma unroll
  for (int ct = 0; ct < 4; ct++) B[ct] = *((const s16x8*)(bptr[ct]));

  __syncthreads();  // vmcnt(0)+lgkmcnt(0)+barrier: staging + B complete

  union { s16x8 v; ushort4 u[2]; } ua;
#pragma unroll
  for (int ks = 0; ks < 8; ks++) {
    s16x8 A[2];
#pragma unroll
    for (int nt = 0; nt < 2; nt++) {
      float4 a0 = *((const float4*)(ap0[nt] + ks * 32));
      float4 a1 = *((const float4*)(ap1[nt] + ks * 32));
      __hip_bfloat162 h0 = __float22bfloat162_rn(make_float2(a0.x, a0.y));
      __hip_bfloat162 h1 = __float22bfloat162_rn(make_float2(a0.z, a0.w));
      __hip_bfloat162 h2 = __float22bfloat162_rn(make_float2(a1.x, a1.y));
      __hip_bfloat162 h3 = __float22bfloat162_rn(make_float2(a1.z, a1.w));
      ua.u[0].x = ((ushort2*)&h0)->x; ua.u[0].y = ((ushort2*)&h0)->y;
      ua.u[0].z = ((ushort2*)&h1)->x; ua.u[0].w = ((ushort2*)&h1)->y;
      ua.u[1].x = ((ushort2*)&h2)->x; ua.u[1].y = ((ushort2*)&h2)->y;
      ua.u[1].z = ((ushort2*)&h3)->x; ua.u[1].w = ((ushort2*)&h3)->y;
      A[nt] = ua.v;
    }
    if (ks < 7) {
#pragma unroll
      for (int ct = 0; ct < 4; ct++)
        Bn[ct] = *((const s16x8*)(bptr[ct] + (size_t)(ks + 1) * 256 * 32));
    }
#pragma unroll
    for (int nt = 0; nt < 2; nt++)
#pragma unroll
      for (int ct = 0; ct < 4; ct++)
        acc[nt][ct] = __builtin_amdgcn_mfma_f32_16x16x32_bf16(
            A[nt], B[ct], acc[nt][ct], 0, 0, 0);
#pragma unroll
    for (int ct = 0; ct < 4; ct++) B[ct] = Bn[ct];
  }

  // --- Epilogue: acc -> LDS bf16 (padded) -> vectorized b128 stores ---
  // C/D layout: col = lane&15, row = (lane>>4)*4 + reg  [m89/m91-verified]
  __syncthreads();  // all A-reads of xs complete before aliasing
  ushort* eb = (ushort*)xs;  // [64][264] bf16 = 33792 B < 64 KiB
#pragma unroll
  for (int nt = 0; nt < 2; nt++) {
#pragma unroll
    for (int ct = 0; ct < 4; ct++) {
      int col = wcol * 64 + ct * 16 + l16;  // 0..255
      float bias = (col >= 128) ? b_l[col - 128] : 0.f;
#pragma unroll
      for (int r = 0; r < 4; r++) {
        int rl = wrow * 32 + nt * 16 + lq * 4 + r;
        eb[rl * 264 + col] = f2bf(acc[nt][ct][r] + bias);
      }
    }
  }
  __syncthreads();
#pragma unroll
  for (int p = 0; p < 4; p++) {
    int id2 = p * 512 + t;      // 0..2047
    int rl = id2 >> 5;          // 0..63
    int c8 = (id2 & 31) * 8;    // 0..248
    int gn = n0 + rl;
    if (gn < N_NODES) {
      s16x8 v = *((const s16x8*)(eb + rl * 264 + c8));
      if (c8 < 128)
        *((s16x8*)(yb + (size_t)gn * D_GNN + c8)) = v;
      else
        *((s16x8*)(yrb + (size_t)gn * D_GNN + (c8 - 128))) = v;
    }
  }
}

// ---------------------------------------------------------------------------
// Gather (padded adjacency, ushort cols) + epilogue + pred head. One wave per
// node; lane owns dims {2*lane, 2*lane+1}. True degree = cursor[node]; first
// min(deg,CAP) neighbors in colp[node*CAP..] (one 64B line), rest in the
// exact overflow list (wave-uniform scan, expected ~0 entries).
// R7: neighbor loop unrolled to 8-deep groups -> 2x loads in flight per wave.
// ---------------------------------------------------------------------------
__global__ __launch_bounds__(256) void gather_pred(
    const int* __restrict__ cursor, const ushort* __restrict__ colp,
    const int* __restrict__ ovcnt, const int2* __restrict__ over,
    const ushort* __restrict__ yb, const ushort* __restrict__ yrb,
    const float* __restrict__ Wfc, const float* __restrict__ bfc,
    float* __restrict__ h, float* __restrict__ pred) {
  const int node = (blockIdx.x * 256 + threadIdx.x) >> 6;
  const int lane = threadIdx.x & 63;
  if (node >= N_NODES) return;
  const int degt = cursor[node];
  const int m = min(degt, CAP);
  float ax = 0.f, ay = 0.f;
  const unsigned int* y32 = (const unsigned int*)yb;

  int c = (lane < m) ? (int)colp[node * CAP + lane] : 0;
  int j = 0;
  for (; j + 8 <= m; j += 8) {  // 8 loads in flight
    int s0 = __shfl(c, j),     s1 = __shfl(c, j + 1);
    int s2 = __shfl(c, j + 2), s3 = __shfl(c, j + 3);
    int s4 = __shfl(c, j + 4), s5 = __shfl(c, j + 5);
    int s6 = __shfl(c, j + 6), s7 = __shfl(c, j + 7);
    unsigned int v0 = y32[(size_t)s0 * 64 + lane];
    unsigned int v1 = y32[(size_t)s1 * 64 + lane];
    unsigned int v2 = y32[(size_t)s2 * 64 + lane];
    unsigned int v3 = y32[(size_t)s3 * 64 + lane];
    unsigned int v4 = y32[(size_t)s4 * 64 + lane];
    unsigned int v5 = y32[(size_t)s5 * 64 + lane];
    unsigned int v6 = y32[(size_t)s6 * 64 + lane];
    unsigned int v7 = y32[(size_t)s7 * 64 + lane];
    ax += __uint_as_float(v0 << 16) + __uint_as_float(v1 << 16) +
          __uint_as_float(v2 << 16) + __uint_as_float(v3 << 16) +
          __uint_as_float(v4 << 16) + __uint_as_float(v5 << 16) +
          __uint_as_float(v6 << 16) + __uint_as_float(v7 << 16);
    ay += __uint_as_float(v0 & 0xFFFF0000u) + __uint_as_float(v1 & 0xFFFF0000u) +
          __uint_as_float(v2 & 0xFFFF0000u) + __uint_as_float(v3 & 0xFFFF0000u) +
          __uint_as_float(v4 & 0xFFFF0000u) + __uint_as_float(v5 & 0xFFFF0000u) +
          __uint_as_float(v6 & 0xFFFF0000u) + __uint_as_float(v7 & 0xFFFF0000u);
  }
  for (; j + 4 <= m; j += 4) {
    int s0 = __shfl(c, j), s1 = __shfl(c, j + 1);
    int s2 = __shfl(c, j + 2), s3 = __shfl(c, j + 3);
    unsigned int v0 = y32[(size_t)s0 * 64 + lane];
    unsigned int v1 = y32[(size_t)s1 * 64 + lane];
    unsigned int v2 = y32[(size_t)s2 * 64 + lane];
    unsigned int v3 = y32[(size_t)s3 * 64 + lane];
    ax += __uint_as_float(v0 << 16) + __uint_as_float(v1 << 16) +
          __uint_as_float(v2 << 16) + __uint_as_float(v3 << 16);
    ay += __uint_as_float(v0 & 0xFFFF0000u) + __uint_as_float(v1 & 0xFFFF0000u) +
          __uint_as_float(v2 & 0xFFFF0000u) + __uint_as_float(v3 & 0xFFFF0000u);
  }
  for (; j < m; j++) {
    int s0 = __shfl(c, j);
    unsigned int v0 = y32[(size_t)s0 * 64 + lane];
    ax += __uint_as_float(v0 << 16);
    ay += __uint_as_float(v0 & 0xFFFF0000u);
  }
  if (degt > CAP) {  // exact overflow handling (rare; wave-uniform)
    int nov = min(ovcnt[0], MAX_OVER);
    for (int k = 0; k < nov; k++) {
      int2 ov = over[k];
      if (ov.x == node) {
        unsigned int v0 = y32[(size_t)ov.y * 64 + lane];
        ax += __uint_as_float(v0 << 16);
        ay += __uint_as_float(v0 & 0xFFFF0000u);
      }
    }
  }

  const float ic = degt > 0 ? 1.f / (float)degt : 0.f;
  unsigned int yrv = ((const unsigned int*)yrb)[(size_t)node * 64 + lane];
  float h0 = ax * ic + __uint_as_float(yrv << 16);
  float h1 = ay * ic + __uint_as_float(yrv & 0xFFFF0000u);
  float2 hv; hv.x = h0; hv.y = h1;
  ((float2*)h)[(size_t)node * 64 + lane] = hv;
  float s = h0 * Wfc[2 * lane] + h1 * Wfc[2 * lane + 1];
#pragma unroll
  for (int off = 32; off > 0; off >>= 1) s += __shfl_down(s, off);
  if (lane == 0) pred[node] = 1.f / (1.f + expf(-(s + bfc[0])));
}

extern "C" void kernel_launch(void* const* d_in, const int* in_sizes, int n_in,
                              void* d_out, int out_size, void* d_ws,
                              size_t ws_size, hipStream_t stream) {
  const float* x   = (const float*)d_in[0];
  const int*   ei  = (const int*)d_in[1];
  const float* Wl  = (const float*)d_in[2];
  const float* bl  = (const float*)d_in[3];
  const float* Wr  = (const float*)d_in[4];
  const float* Wfc = (const float*)d_in[5];
  const float* bfc = (const float*)d_in[6];

  float* out  = (float*)d_out;
  float* h    = out;                        // [N,128] final h (f32)
  float* pred = out + (size_t)N_NODES * D_GNN;

  ushort* Wcp   = (ushort*)d_ws;                              // 128 KB
  ushort* yb    = Wcp + 8192 * 8;                             // [N,128] bf16
  ushort* yrb   = yb + (size_t)N_NODES * D_GNN;               // [N,128] bf16
  int*   cursor = (int*)(yrb + (size_t)N_NODES * D_GNN);      // [N]
  int*   ovcnt  = cursor + N_NODES;                           // [1]
  int2*  over   = (int2*)(ovcnt + 1);                         // [MAX_OVER]
  ushort* colp  = (ushort*)(over + MAX_OVER);                 // [N*CAP] ushort

  // --- prologue: zero cursor/ovcnt + pack W ---
  pack0<<<(N_NODES + 255) / 256, 256, 0, stream>>>(Wl, Wr, Wcp, cursor, ovcnt);

  // --- fused: 64 edge-build blocks (first) + 782 pure-GEMM blocks ---
  fused_gemm_fill<<<EDGE_BLKS + (N_NODES + 63) / 64, 512, 0, stream>>>(
      x, Wcp, bl, ei, cursor, colp, ovcnt, over, yb, yrb);

  // --- mean gather + h epilogue + pred head ---
  gather_pred<<<(N_NODES * 64 + 255) / 256, 256, 0, stream>>>(
      cursor, colp, ovcnt, over, yb, yrb, Wfc, bfc, h, pred);
}

// Round 10
// 170.056 us; speedup vs baseline: 1.0464x; 1.0464x over previous
//
#include <hip/hip_runtime.h>
#include <hip/hip_bf16.h>
#include <math.h>

#define N_NODES 50000
#define N_EDGES 600000
#define D_IN 256
#define D_GNN 128
#define CAP 32        // padded adjacency slots per node (ushort); 1 cache line
#define MAX_OVER 8192

typedef short s16x8 __attribute__((ext_vector_type(8)));
typedef float f32x4 __attribute__((ext_vector_type(4)));

__device__ __forceinline__ unsigned short f2bf(float f) {
  unsigned int u = __float_as_uint(f);
  u += 0x7FFFu + ((u >> 16) & 1u);  // RNE
  return (unsigned short)(u >> 16);
}

// ---------------------------------------------------------------------------
// Prologue: zero cursor[] + overflow count + pack Wc=[W_l|W_r] to B-fragment
// order (bf16): Wcp[((ks*256+col)*4+q)*8+j] = [Wl|Wr][ks*32+q*8+j][col]
// ---------------------------------------------------------------------------
__global__ __launch_bounds__(256) void pack0(
    const float* __restrict__ Wl, const float* __restrict__ Wr,
    ushort* __restrict__ Wcp, int* __restrict__ cursor,
    int* __restrict__ ovcnt) {
  int i = blockIdx.x * 256 + threadIdx.x;
  if (i < N_NODES) cursor[i] = 0;
  if (i == 0) ovcnt[0] = 0;
  if (i < 8192) {  // one 16B B-fragment per thread
    int q = i & 3, col = (i >> 2) & 255, ks = i >> 10;
    const float* W = (col < 128) ? Wl : Wr;
    int c = col & 127;
    int k0 = ks * 32 + q * 8;
    s16x8 v;
#pragma unroll
    for (int j = 0; j < 8; j++) v[j] = (short)f2bf(W[(k0 + j) * D_GNN + c]);
    *((s16x8*)(Wcp + (size_t)i * 8)) = v;
  }
}

// ---------------------------------------------------------------------------
// FUSED kernel (R10 = best measured cell of the R2/R6/R7 matrix): MFMA GEMM
// + inline edge adjacency build.
//   Matrix: R2 (inline, compact, int colp) fused=56 total=174.7; R6 (inline,
//   padded, ushort) 63/170.8; R7 (specialized, compact, ushort) 63/178.
//   This round: inline + compact cursor + ushort colp (gather's ~11us win)
//   + B-fragment loads hoisted BEFORE the edge loop so B L2 latency overlaps
//   the edge atomics instead of sitting exposed before the barrier.
//   Monolith/grid-barrier abandoned: 2x container kills (R8/R9).
//   GEMM: [y_l|y_r] = x @ [W_l|W_r]; block = 64 rows x 256 cols, 8 waves;
//   x staged f32->LDS via async global_load_lds w=16 (source-chunk swizzle,
//   read-side same involution); bf16 cvt at A-read; B prefetch 1 K-step.
//   Epilogue: acc -> LDS bf16 (stride 264, 0-conflict) -> b128 stores.
// ---------------------------------------------------------------------------
__global__ __launch_bounds__(512, 4) void fused_gemm_fill(
    const float* __restrict__ x, const ushort* __restrict__ Wcp,
    const float* __restrict__ b_l, const int* __restrict__ ei,
    int* __restrict__ cursor, ushort* __restrict__ colp,
    int* __restrict__ ovcnt, int2* __restrict__ over,
    ushort* __restrict__ yb, ushort* __restrict__ yrb) {
  __shared__ float xs[64 * 256];  // 64 KiB staging; epilogue aliases as bf16
  const int t = threadIdx.x;
  const int n0 = blockIdx.x * 64;
  const int l = t & 63;
  const int w = t >> 6;

  // --- 1. async stage x -> LDS (f32, source-chunk swizzled) ---
#pragma unroll
  for (int j = 0; j < 8; j++) {
    const int row = j * 8 + w;
    int gn = n0 + row;
    if (gn >= N_NODES) gn = N_NODES - 1;  // clamp; stores guarded
    const int sc = (l & ~7) | ((l & 7) ^ (row & 7));
    __builtin_amdgcn_global_load_lds(
        (const __attribute__((address_space(1))) unsigned int*)(
            x + (size_t)gn * 256 + sc * 4),
        (__attribute__((address_space(3))) unsigned int*)(xs + row * 256),
        16, 0, 0);
  }

  const int wrow = w & 1;
  const int wcol = w >> 1;
  const int lq = l >> 4, l16 = l & 15;

  // --- 2. B pointers + FIRST B fragments issued now: their L2 latency
  //        overlaps the edge-atomic phase below (R2 had them after it) ---
  const ushort* bptr[4];
#pragma unroll
  for (int ct = 0; ct < 4; ct++) {
    int col = wcol * 64 + ct * 16 + l16;
    bptr[ct] = Wcp + ((size_t)col * 4 + lq) * 8;
  }
  s16x8 B[4], Bn[4];
#pragma unroll
  for (int ct = 0; ct < 4; ct++) B[ct] = *((const s16x8*)(bptr[ct]));

  // --- 3. edge work (drains under staging + B-load latency) ---
  {
    const int stride = gridDim.x * 512;
    for (int e = blockIdx.x * 512 + t; e < N_EDGES; e += stride) {
      int src = ei[e];
      int dst = ei[N_EDGES + e];
      int pos = atomicAdd(&cursor[dst], 1);
      if (pos < CAP) {
        colp[dst * CAP + pos] = (ushort)src;
      } else {
        int o = atomicAdd(ovcnt, 1);
        if (o < MAX_OVER) over[o] = make_int2(dst, src);
      }
    }
  }

  f32x4 acc[2][4];
#pragma unroll
  for (int a = 0; a < 2; a++)
#pragma unroll
    for (int b = 0; b < 4; b++) acc[a][b] = (f32x4){0.f, 0.f, 0.f, 0.f};

  // A-read bases: row rl, chunk pair (ks*8 + o0), o0 = (lq*2)^(rl&7).
  const float* ap0[2];
  const float* ap1[2];
#pragma unroll
  for (int nt = 0; nt < 2; nt++) {
    int rl = wrow * 32 + nt * 16 + l16;
    int o0 = (lq * 2) ^ (rl & 7);
    ap0[nt] = xs + rl * 256 + o0 * 4;
    ap1[nt] = xs + rl * 256 + (o0 ^ 1) * 4;
  }

  __syncthreads();  // vmcnt(0)+lgkmcnt(0)+barrier: staging+edges+B complete

  union { s16x8 v; ushort4 u[2]; } ua;
#pragma unroll
  for (int ks = 0; ks < 8; ks++) {
    s16x8 A[2];
#pragma unroll
    for (int nt = 0; nt < 2; nt++) {
      float4 a0 = *((const float4*)(ap0[nt] + ks * 32));
      float4 a1 = *((const float4*)(ap1[nt] + ks * 32));
      __hip_bfloat162 h0 = __float22bfloat162_rn(make_float2(a0.x, a0.y));
      __hip_bfloat162 h1 = __float22bfloat162_rn(make_float2(a0.z, a0.w));
      __hip_bfloat162 h2 = __float22bfloat162_rn(make_float2(a1.x, a1.y));
      __hip_bfloat162 h3 = __float22bfloat162_rn(make_float2(a1.z, a1.w));
      ua.u[0].x = ((ushort2*)&h0)->x; ua.u[0].y = ((ushort2*)&h0)->y;
      ua.u[0].z = ((ushort2*)&h1)->x; ua.u[0].w = ((ushort2*)&h1)->y;
      ua.u[1].x = ((ushort2*)&h2)->x; ua.u[1].y = ((ushort2*)&h2)->y;
      ua.u[1].z = ((ushort2*)&h3)->x; ua.u[1].w = ((ushort2*)&h3)->y;
      A[nt] = ua.v;
    }
    if (ks < 7) {
#pragma unroll
      for (int ct = 0; ct < 4; ct++)
        Bn[ct] = *((const s16x8*)(bptr[ct] + (size_t)(ks + 1) * 256 * 32));
    }
#pragma unroll
    for (int nt = 0; nt < 2; nt++)
#pragma unroll
      for (int ct = 0; ct < 4; ct++)
        acc[nt][ct] = __builtin_amdgcn_mfma_f32_16x16x32_bf16(
            A[nt], B[ct], acc[nt][ct], 0, 0, 0);
#pragma unroll
    for (int ct = 0; ct < 4; ct++) B[ct] = Bn[ct];
  }

  // --- Epilogue: acc -> LDS bf16 (padded) -> vectorized b128 stores ---
  // C/D layout: col = lane&15, row = (lane>>4)*4 + reg  [m89/m91-verified]
  __syncthreads();  // all A-reads of xs complete before aliasing
  ushort* eb = (ushort*)xs;  // [64][264] bf16 = 33792 B < 64 KiB
#pragma unroll
  for (int nt = 0; nt < 2; nt++) {
#pragma unroll
    for (int ct = 0; ct < 4; ct++) {
      int col = wcol * 64 + ct * 16 + l16;  // 0..255
      float bias = (col >= 128) ? b_l[col - 128] : 0.f;
#pragma unroll
      for (int r = 0; r < 4; r++) {
        int rl = wrow * 32 + nt * 16 + lq * 4 + r;
        eb[rl * 264 + col] = f2bf(acc[nt][ct][r] + bias);
      }
    }
  }
  __syncthreads();
#pragma unroll
  for (int p = 0; p < 4; p++) {
    int id2 = p * 512 + t;      // 0..2047
    int rl = id2 >> 5;          // 0..63
    int c8 = (id2 & 31) * 8;    // 0..248
    int gn = n0 + rl;
    if (gn < N_NODES) {
      s16x8 v = *((const s16x8*)(eb + rl * 264 + c8));
      if (c8 < 128)
        *((s16x8*)(yb + (size_t)gn * D_GNN + c8)) = v;
      else
        *((s16x8*)(yrb + (size_t)gn * D_GNN + (c8 - 128))) = v;
    }
  }
}

// ---------------------------------------------------------------------------
// Gather (padded adjacency, ushort cols) + epilogue + pred head. One wave per
// node; lane owns dims {2*lane, 2*lane+1}. True degree = cursor[node]; first
// min(deg,CAP) neighbors in colp[node*CAP..] (one 64B line), rest in the
// exact overflow list (wave-uniform scan, expected ~0 entries).
// 4-deep unroll (R6-proven; R7's 8-deep regressed -> reverted).
// ---------------------------------------------------------------------------
__global__ __launch_bounds__(256) void gather_pred(
    const int* __restrict__ cursor, const ushort* __restrict__ colp,
    const int* __restrict__ ovcnt, const int2* __restrict__ over,
    const ushort* __restrict__ yb, const ushort* __restrict__ yrb,
    const float* __restrict__ Wfc, const float* __restrict__ bfc,
    float* __restrict__ h, float* __restrict__ pred) {
  const int node = (blockIdx.x * 256 + threadIdx.x) >> 6;
  const int lane = threadIdx.x & 63;
  if (node >= N_NODES) return;
  const int degt = cursor[node];
  const int m = min(degt, CAP);
  float ax = 0.f, ay = 0.f;
  const unsigned int* y32 = (const unsigned int*)yb;

  int c = (lane < m) ? (int)colp[node * CAP + lane] : 0;
  int j = 0;
  for (; j + 4 <= m; j += 4) {
    int s0 = __shfl(c, j), s1 = __shfl(c, j + 1);
    int s2 = __shfl(c, j + 2), s3 = __shfl(c, j + 3);
    unsigned int v0 = y32[(size_t)s0 * 64 + lane];
    unsigned int v1 = y32[(size_t)s1 * 64 + lane];
    unsigned int v2 = y32[(size_t)s2 * 64 + lane];
    unsigned int v3 = y32[(size_t)s3 * 64 + lane];
    ax += __uint_as_float(v0 << 16) + __uint_as_float(v1 << 16) +
          __uint_as_float(v2 << 16) + __uint_as_float(v3 << 16);
    ay += __uint_as_float(v0 & 0xFFFF0000u) + __uint_as_float(v1 & 0xFFFF0000u) +
          __uint_as_float(v2 & 0xFFFF0000u) + __uint_as_float(v3 & 0xFFFF0000u);
  }
  for (; j < m; j++) {
    int s0 = __shfl(c, j);
    unsigned int v0 = y32[(size_t)s0 * 64 + lane];
    ax += __uint_as_float(v0 << 16);
    ay += __uint_as_float(v0 & 0xFFFF0000u);
  }
  if (degt > CAP) {  // exact overflow handling (rare; wave-uniform)
    int nov = min(ovcnt[0], MAX_OVER);
    for (int k = 0; k < nov; k++) {
      int2 ov = over[k];
      if (ov.x == node) {
        unsigned int v0 = y32[(size_t)ov.y * 64 + lane];
        ax += __uint_as_float(v0 << 16);
        ay += __uint_as_float(v0 & 0xFFFF0000u);
      }
    }
  }

  const float ic = degt > 0 ? 1.f / (float)degt : 0.f;
  unsigned int yrv = ((const unsigned int*)yrb)[(size_t)node * 64 + lane];
  float h0 = ax * ic + __uint_as_float(yrv << 16);
  float h1 = ay * ic + __uint_as_float(yrv & 0xFFFF0000u);
  float2 hv; hv.x = h0; hv.y = h1;
  ((float2*)h)[(size_t)node * 64 + lane] = hv;
  float s = h0 * Wfc[2 * lane] + h1 * Wfc[2 * lane + 1];
#pragma unroll
  for (int off = 32; off > 0; off >>= 1) s += __shfl_down(s, off);
  if (lane == 0) pred[node] = 1.f / (1.f + expf(-(s + bfc[0])));
}

extern "C" void kernel_launch(void* const* d_in, const int* in_sizes, int n_in,
                              void* d_out, int out_size, void* d_ws,
                              size_t ws_size, hipStream_t stream) {
  const float* x   = (const float*)d_in[0];
  const int*   ei  = (const int*)d_in[1];
  const float* Wl  = (const float*)d_in[2];
  const float* bl  = (const float*)d_in[3];
  const float* Wr  = (const float*)d_in[4];
  const float* Wfc = (const float*)d_in[5];
  const float* bfc = (const float*)d_in[6];

  float* out  = (float*)d_out;
  float* h    = out;                        // [N,128] final h (f32)
  float* pred = out + (size_t)N_NODES * D_GNN;

  ushort* Wcp   = (ushort*)d_ws;                              // 128 KB
  ushort* yb    = Wcp + 8192 * 8;                             // [N,128] bf16
  ushort* yrb   = yb + (size_t)N_NODES * D_GNN;               // [N,128] bf16
  int*   cursor = (int*)(yrb + (size_t)N_NODES * D_GNN);      // [N]
  int*   ovcnt  = cursor + N_NODES;                           // [1]
  int2*  over   = (int2*)(ovcnt + 1);                         // [MAX_OVER]
  ushort* colp  = (ushort*)(over + MAX_OVER);                 // [N*CAP] ushort

  // --- prologue: zero cursor/ovcnt + pack W ---
  pack0<<<(N_NODES + 255) / 256, 256, 0, stream>>>(Wl, Wr, Wcp, cursor, ovcnt);

  // --- fused: adjacency build (overlapped) + y_l|y_r GEMM ---
  fused_gemm_fill<<<(N_NODES + 63) / 64, 512, 0, stream>>>(
      x, Wcp, bl, ei, cursor, colp, ovcnt, over, yb, yrb);

  // --- mean gather + h epilogue + pred head ---
  gather_pred<<<(N_NODES * 64 + 255) / 256, 256, 0, stream>>>(
      cursor, colp, ovcnt, over, yb, yrb, Wfc, bfc, h, pred);
}